// Round 1
// baseline (156.816 us; speedup 1.0000x reference)
//
#include <hip/hip_runtime.h>

typedef __attribute__((ext_vector_type(8))) short short8;
typedef __attribute__((ext_vector_type(4))) float f32x4;
typedef unsigned short u16;

#define BB 4
#define TT 4096
#define CC 1024
#define HH 64

static __device__ __forceinline__ u16 f2bf(float f) {
    unsigned int u = __float_as_uint(f);
    unsigned int r = (u + 0x7FFFu + ((u >> 16) & 1u)) >> 16;  // RNE
    return (u16)r;
}

// attn LDS tile addressing: 64-u16 rows, 8 chunks of 8 u16; chunk XOR-swizzled by row&7.
static __device__ __forceinline__ int swz(int row, int chunk) {
    return row * 64 + ((chunk ^ (row & 7)) << 3);
}

// ---------------- dtype probe: flag=1 -> bf16 buffers, flag=0 -> f32 buffers.
__global__ void detect_dtype(const u16* __restrict__ xu, int* __restrict__ flag) {
    int lane = threadIdx.x;
    int cnt = 0;
    for (int i = lane; i < 1024; i += 64) {
        u16 u = xu[2 * i];
        int e = (u >> 7) & 0xFF;
        cnt += (e >= 100 && e <= 140) ? 1 : 0;
    }
    for (int d = 1; d < 64; d <<= 1) cnt += __shfl_xor(cnt, d);
    if (lane == 0) *flag = (cnt > 512) ? 1 : 0;
}

// ---------------- W -> Wtp packed B-fragment order.
// Wtp 16B-chunk index: (((proj*4+nt)*16 + kb)*2 + k2)*64 + quad*16 + l15
// holding W[k = kb*64+k2*32+quad*8 .. +8][n = proj*64+nt*16+l15].
__global__ void wt_transpose(const void* __restrict__ Wk, const void* __restrict__ Wq,
                             const void* __restrict__ Wv, u16* __restrict__ Wtp,
                             const int* __restrict__ flag) {
    const int isbf = *flag;
    int r = blockIdx.x;          // global output col 0..191
    int p = r >> 6;              // 0=q 1=k 2=v
    int n = r & 63;
    int nt = n >> 4, nl = n & 15;
    const void* W = (p == 0) ? Wq : (p == 1) ? Wk : Wv;
    int k0 = threadIdx.x * 4;    // 4 consecutive k per thread
    int kb = k0 >> 6, k2 = (k0 >> 5) & 1, quad = (k0 >> 3) & 3, half = (k0 >> 2) & 1;
    ushort4 v;
    if (isbf) {
        const u16* Wb = (const u16*)W;
        v.x = Wb[(k0 + 0) * HH + n]; v.y = Wb[(k0 + 1) * HH + n];
        v.z = Wb[(k0 + 2) * HH + n]; v.w = Wb[(k0 + 3) * HH + n];
    } else {
        const float* Wf = (const float*)W;
        v.x = f2bf(Wf[(k0 + 0) * HH + n]); v.y = f2bf(Wf[(k0 + 1) * HH + n]);
        v.z = f2bf(Wf[(k0 + 2) * HH + n]); v.w = f2bf(Wf[(k0 + 3) * HH + n]);
    }
    size_t off16 = ((size_t)((p * 4 + nt) * 16 + kb) * 2 + k2) * 64 + quad * 16 + nl;
    *reinterpret_cast<ushort4*>(Wtp + off16 * 8 + half * 4) = v;
}

// ---------------- QKV projection v4: fused LDS transpose, one barrier.
// 1024 blocks x 256 thr (4 waves). Block = 16 rows of x; the FULL K=1024 is staged
// into 32KB LDS with contiguous global reads, then the k-loop runs barrier-free:
// A-frags from LDS (swizzled), B-frags from L2-resident Wtp (contiguous 1KB/instr).
// Wave w computes col-tile w of each of q,k,v.
__global__ __launch_bounds__(256) void qkv_proj(const void* __restrict__ x,
                                                const u16* __restrict__ Wtp,
                                                u16* __restrict__ qo, u16* __restrict__ ko,
                                                u16* __restrict__ vo, const int* __restrict__ flag) {
    __shared__ __align__(16) u16 xs[16 * 1024];   // [row][k], 16B chunks swizzled by row&7
    __shared__ __align__(16) u16 tls[4][3][256];  // per-wave, per-proj 16x16 transpose tile
    const int isbf = *flag;
    const int tid = threadIdx.x;
    const int lane = tid & 63;
    const int w = tid >> 6;
    const int l15 = lane & 15;
    const int quad = lane >> 4;
    int phys = blockIdx.x;
    int rb = (phys & 7) * 128 + (phys >> 3);      // XCD-affine 16-row group, 0..1023
    const int g0r = rb * 16;

    // ---- stage 16 rows of x (contiguous reads; swizzled 16B-chunk writes)
    #pragma unroll
    for (int j = 0; j < 8; j++) {
        int c = tid + j * 256;                    // 2048 chunks: row = c>>7, ck = c&127
        int row = c >> 7, ck = c & 127;
        int dst = row * 1024 + ((ck ^ (row & 7)) << 3);
        if (isbf) {
            uint4 d = *reinterpret_cast<const uint4*>((const u16*)x + (size_t)(g0r + row) * CC + ck * 8);
            *reinterpret_cast<uint4*>(xs + dst) = d;
        } else {
            const float4* pf = reinterpret_cast<const float4*>((const float*)x + (size_t)(g0r + row) * CC + ck * 8);
            float4 a0 = pf[0], a1 = pf[1];
            ushort4 lo; lo.x = f2bf(a0.x); lo.y = f2bf(a0.y); lo.z = f2bf(a0.z); lo.w = f2bf(a0.w);
            ushort4 hi; hi.x = f2bf(a1.x); hi.y = f2bf(a1.y); hi.z = f2bf(a1.z); hi.w = f2bf(a1.w);
            *reinterpret_cast<ushort4*>(xs + dst) = lo;
            *reinterpret_cast<ushort4*>(xs + dst + 4) = hi;
        }
    }
    __syncthreads();                              // the ONLY block-wide barrier

    f32x4 zero = {0.f, 0.f, 0.f, 0.f};
    f32x4 acc[3];                                 // proj 0=q 1=k 2=v, col-tile w each
    #pragma unroll
    for (int i = 0; i < 3; i++) acc[i] = zero;

    for (int kb = 0; kb < 16; kb++) {
        #pragma unroll
        for (int k2 = 0; k2 < 2; k2++) {
            int ck = kb * 8 + k2 * 4 + quad;
            short8 af = *reinterpret_cast<const short8*>(xs + l15 * 1024 + ((ck ^ (l15 & 7)) << 3));
            #pragma unroll
            for (int p = 0; p < 3; p++) {
                short8 bf = *reinterpret_cast<const short8*>(
                    Wtp + ((((size_t)(p * 4 + w) * 16 + kb) * 2 + k2) * 64 + lane) * 8);
                acc[p] = __builtin_amdgcn_mfma_f32_16x16x32_bf16(af, bf, acc[p], 0, 0, 0);
            }
        }
    }

    // ---- epilogue: per-wave 16x16 LDS transpose, 8B coalesced stores
    const float qscale = 0.18033688011112042f;    // log2(e)/8
    #pragma unroll
    for (int p = 0; p < 3; p++) {
        if (p < 2) {
            float sc = (p == 0) ? qscale : 1.f;
            #pragma unroll
            for (int r = 0; r < 4; r++)           // [t(16)][c(16)]
                tls[w][p][(quad * 4 + r) * 16 + l15] = f2bf(acc[p][r] * sc);
        } else {
            #pragma unroll
            for (int r = 0; r < 4; r++)           // [c(16)][t(16)]
                tls[w][p][l15 * 16 + quad * 4 + r] = f2bf(acc[p][r]);
        }
    }
    // same-wave LDS RAW: compiler inserts lgkmcnt wait; no barrier needed
    #pragma unroll
    for (int p = 0; p < 2; p++) {                 // q, k: row-major (g0r+t)*64 + w*16+c
        int t = lane >> 2, seg = lane & 3;
        ushort4 d = *reinterpret_cast<const ushort4*>(&tls[w][p][t * 16 + seg * 4]);
        u16* dst = (p == 0) ? qo : ko;
        *reinterpret_cast<ushort4*>(dst + (size_t)(g0r + t) * HH + w * 16 + seg * 4) = d;
    }
    {                                             // v: vo[b][kt][h][64keys]
        int c = lane >> 2, seg = lane & 3;
        ushort4 d = *reinterpret_cast<const ushort4*>(&tls[w][2][c * 16 + seg * 4]);
        int b = rb >> 8;
        int kt = (g0r & 4095) >> 6;
        int toff = g0r & 63;
        *reinterpret_cast<ushort4*>(vo + ((size_t)((b * 64 + kt) * 64 + w * 16 + c)) * 64 + toff + seg * 4) = d;
    }
}

// ---------------- causal flash attention, 64 q-rows/block, split-K over 64-key tiles.
// vo is ktile-packed -> both K and V staging are contiguous 8KB reads.
// Split-K combine is SLOT-BASED (no atomics): split ks writes partial O to
// acco + ks*B*T*H and partial l to accl + ks*B*T with plain stores; finalize sums.
__global__ __launch_bounds__(256) void attn(const u16* __restrict__ qp, const u16* __restrict__ kp,
                                            const u16* __restrict__ vp, float* __restrict__ acco,
                                            float* __restrict__ accl, void* __restrict__ outv,
                                            const int* __restrict__ flag, int nsplit) {
    __shared__ __align__(16) u16 kst[64 * 64];   // (key, h), swizzled
    __shared__ __align__(16) u16 vts[64 * 64];   // (h, key), swizzled
    __shared__ __align__(16) u16 pb[4][16 * 64]; // per-wave P
    const int isbf = *flag;
    const int tid = threadIdx.x;
    const int lane = tid & 63;
    const int w = tid >> 6;           // 0..3
    const int l15 = lane & 15;
    const int quad = lane >> 4;

    int u = blockIdx.x;
    int b, qt, ks;
    if (nsplit == 1) {
        b = u >> 6;
        int raw = u & 63;
        qt = (raw & 1) ? (63 - (raw >> 1)) : (raw >> 1);
        ks = 0;
    } else {
        int per = 64 * nsplit;
        b = u / per;
        int rem = u - b * per;
        qt = rem / nsplit;
        ks = rem - qt * nsplit;
    }
    int qbase = qt * 64;
    int diag = qt;
    int nkt = diag + 1;
    if (ks >= nkt) return;

    short8 aq[2];
    {
        const u16* qrow = qp + (size_t)(b * TT + qbase + w * 16 + l15) * HH;
        aq[0] = *reinterpret_cast<const short8*>(qrow + quad * 8);
        aq[1] = *reinterpret_cast<const short8*>(qrow + 32 + quad * 8);
    }

    f32x4 zero = {0.f, 0.f, 0.f, 0.f};
    f32x4 o[4];
    #pragma unroll
    for (int i = 0; i < 4; i++) o[i] = zero;
    f32x4 lsum = zero;

    for (int kt = ks; kt < nkt; kt += nsplit) {
        __syncthreads();              // previous iter's LDS reads done
        #pragma unroll
        for (int j = 0; j < 2; j++) {
            int cc = tid + j * 256;   // 512 chunks each, contiguous sources
            int row = cc >> 3, c8 = cc & 7;
            int dst = swz(row, c8);
            uint4 dk = *reinterpret_cast<const uint4*>(kp + (size_t)(b * TT + kt * 64) * HH + cc * 8);
            *reinterpret_cast<uint4*>(&kst[dst]) = dk;
            uint4 dv = *reinterpret_cast<const uint4*>(vp + ((size_t)(b * 64 + kt)) * 64 * 64 + cc * 8);
            *reinterpret_cast<uint4*>(&vts[dst]) = dv;
        }
        __syncthreads();              // staging visible
        // S = Q K^T (log2 domain via q pre-scale)
        f32x4 s[4];
        #pragma unroll
        for (int i = 0; i < 4; i++) s[i] = zero;
        #pragma unroll
        for (int k2 = 0; k2 < 2; k2++) {
            #pragma unroll
            for (int nt = 0; nt < 4; nt++) {
                short8 bf = *reinterpret_cast<const short8*>(&kst[swz(nt * 16 + l15, k2 * 4 + quad)]);
                s[nt] = __builtin_amdgcn_mfma_f32_16x16x32_bf16(aq[k2], bf, s[nt], 0, 0, 0);
            }
        }
        // p = exp2(s), causal mask on diagonal tile
        const int rg = qbase + w * 16 + quad * 4;
        const bool dm = (kt == diag);
        #pragma unroll
        for (int nt = 0; nt < 4; nt++) {
            int key = kt * 64 + nt * 16 + l15;
            #pragma unroll
            for (int r = 0; r < 4; r++) {
                float p = __builtin_amdgcn_exp2f(s[nt][r]);
                if (dm && key > rg + r) p = 0.f;
                s[nt][r] = p;
            }
        }
        #pragma unroll
        for (int nt = 0; nt < 4; nt++) lsum = lsum + s[nt];
        // P (C/D layout) -> per-wave LDS A-layout (same-wave RAW)
        #pragma unroll
        for (int nt = 0; nt < 4; nt++) {
            int chunk = nt * 2 + (l15 >> 3);
            int off = l15 & 7;
            #pragma unroll
            for (int r = 0; r < 4; r++) {
                int row = quad * 4 + r;
                pb[w][row * 64 + ((chunk ^ (row & 7)) << 3) + off] = f2bf(s[nt][r]);
            }
        }
        // O += P V
        #pragma unroll
        for (int k2 = 0; k2 < 2; k2++) {
            short8 ap = *reinterpret_cast<const short8*>(&pb[w][swz(l15, k2 * 4 + quad)]);
            #pragma unroll
            for (int nt = 0; nt < 4; nt++) {
                short8 bv = *reinterpret_cast<const short8*>(&vts[swz(nt * 16 + l15, k2 * 4 + quad)]);
                o[nt] = __builtin_amdgcn_mfma_f32_16x16x32_bf16(ap, bv, o[nt], 0, 0, 0);
            }
        }
    }

    #pragma unroll
    for (int d = 1; d < 16; d <<= 1) {
        f32x4 t;
        #pragma unroll
        for (int r = 0; r < 4; r++) t[r] = __shfl_xor(lsum[r], d);
        lsum = lsum + t;
    }
    const int g0 = b * TT + qbase + w * 16 + quad * 4;

    if (nsplit == 1) {
        f32x4 inv;
        #pragma unroll
        for (int r = 0; r < 4; r++) inv[r] = 1.0f / lsum[r];
        if (isbf) {
            u16* outp = (u16*)outv;
            #pragma unroll
            for (int nt = 0; nt < 4; nt++)
                #pragma unroll
                for (int r = 0; r < 4; r++)
                    outp[(size_t)(g0 + r) * HH + nt * 16 + l15] = f2bf(o[nt][r] * inv[r]);
        } else {
            float* outp = (float*)outv;
            #pragma unroll
            for (int nt = 0; nt < 4; nt++)
                #pragma unroll
                for (int r = 0; r < 4; r++)
                    outp[(size_t)(g0 + r) * HH + nt * 16 + l15] = o[nt][r] * inv[r];
        }
    } else {
        // slot-based partial writes: each (b,qt,ks) owns distinct rows of its slot
        float* accos = acco + (size_t)ks * (BB * TT * HH);
        float* accls = accl + (size_t)ks * (BB * TT);
        #pragma unroll
        for (int nt = 0; nt < 4; nt++)
            #pragma unroll
            for (int r = 0; r < 4; r++)
                accos[(size_t)(g0 + r) * HH + nt * 16 + l15] = o[nt][r];
        if (l15 == 0) {
            #pragma unroll
            for (int r = 0; r < 4; r++) accls[g0 + r] = lsum[r];
        }
    }
}

// ---------------- finalize: out = (sum over active slots of acco) / (sum accl)
__global__ __launch_bounds__(256) void attn_finalize(const float* __restrict__ acco,
                                                     const float* __restrict__ accl,
                                                     void* __restrict__ outv,
                                                     const int* __restrict__ flag, int nsplit) {
    const int isbf = *flag;
    int i = blockIdx.x * blockDim.x + threadIdx.x;   // float4 index over B*T*H
    int row = i >> 4;
    int qt = (row & (TT - 1)) >> 6;
    int nact = min(nsplit, qt + 1);
    float4 ov = reinterpret_cast<const float4*>(acco)[i];
    float l = accl[row];
    for (int s = 1; s < nact; s++) {
        float4 t = reinterpret_cast<const float4*>(acco + (size_t)s * (BB * TT * HH))[i];
        ov.x += t.x; ov.y += t.y; ov.z += t.z; ov.w += t.w;
        l += accl[(size_t)s * (BB * TT) + row];
    }
    float inv = 1.0f / l;
    if (isbf) {
        ushort4 s;
        s.x = f2bf(ov.x * inv); s.y = f2bf(ov.y * inv);
        s.z = f2bf(ov.z * inv); s.w = f2bf(ov.w * inv);
        reinterpret_cast<ushort4*>(outv)[i] = s;
    } else {
        float4 s = {ov.x * inv, ov.y * inv, ov.z * inv, ov.w * inv};
        reinterpret_cast<float4*>(outv)[i] = s;
    }
}

extern "C" void kernel_launch(void* const* d_in, const int* in_sizes, int n_in,
                              void* d_out, int out_size, void* d_ws, size_t ws_size,
                              hipStream_t stream) {
    const void* x  = d_in[0];
    const void* Wk = d_in[1];
    const void* Wq = d_in[2];
    const void* Wv = d_in[3];
    char* ws = (char*)d_ws;
    // ws: qo 0-2M | ko 2-4M | vo 4-6M | Wtp @6M(384K) | flag @6.75M
    //     acco @7M (nsplit slots x 4M = 16M) | accl @23M (nsplit slots x 64K = 256K)
    u16* qo = (u16*)(ws);
    u16* ko = (u16*)(ws + (size_t)2 * 1024 * 1024);
    u16* vo = (u16*)(ws + (size_t)4 * 1024 * 1024);
    u16* Wtp = (u16*)(ws + (size_t)6 * 1024 * 1024);
    int* flag = (int*)(ws + (size_t)6 * 1024 * 1024 + 768 * 1024);
    float* acco = (float*)(ws + (size_t)7 * 1024 * 1024);
    float* accl = (float*)(ws + (size_t)23 * 1024 * 1024);

    const size_t need_split = (size_t)24 * 1024 * 1024;
    const int nsplit = (ws_size >= need_split) ? 4 : 1;

    detect_dtype<<<1, 64, 0, stream>>>((const u16*)x, flag);
    wt_transpose<<<192, 256, 0, stream>>>(Wk, Wq, Wv, Wtp, flag);
    qkv_proj<<<1024, 256, 0, stream>>>(x, Wtp, qo, ko, vo, flag);
    if (nsplit > 1) {
        attn<<<BB * 64 * nsplit, 256, 0, stream>>>(qo, ko, vo, acco, accl, d_out, flag, nsplit);
        attn_finalize<<<(BB * TT * HH / 4) / 256, 256, 0, stream>>>(acco, accl, d_out, flag, nsplit);
    } else {
        attn<<<BB * 64, 256, 0, stream>>>(qo, ko, vo, acco, accl, d_out, flag, 1);
    }
}

// Round 2
// 146.206 us; speedup vs baseline: 1.0726x; 1.0726x over previous
//
#include <hip/hip_runtime.h>

typedef __attribute__((ext_vector_type(8))) short short8;
typedef __attribute__((ext_vector_type(4))) float f32x4;
typedef unsigned short u16;

#define BB 4
#define TT 4096
#define CC 1024
#define HH 64

static __device__ __forceinline__ u16 f2bf(float f) {
    unsigned int u = __float_as_uint(f);
    unsigned int r = (u + 0x7FFFu + ((u >> 16) & 1u)) >> 16;  // RNE
    return (u16)r;
}

// attn LDS tile addressing: 64-u16 rows, 8 chunks of 8 u16; chunk XOR-swizzled by row&7.
static __device__ __forceinline__ int swz(int row, int chunk) {
    return row * 64 + ((chunk ^ (row & 7)) << 3);
}

// ---------------- dtype probe: flag=1 -> bf16 buffers, flag=0 -> f32 buffers.
__global__ void detect_dtype(const u16* __restrict__ xu, int* __restrict__ flag) {
    int lane = threadIdx.x;
    int cnt = 0;
    for (int i = lane; i < 1024; i += 64) {
        u16 u = xu[2 * i];
        int e = (u >> 7) & 0xFF;
        cnt += (e >= 100 && e <= 140) ? 1 : 0;
    }
    for (int d = 1; d < 64; d <<= 1) cnt += __shfl_xor(cnt, d);
    if (lane == 0) *flag = (cnt > 512) ? 1 : 0;
}

// ---------------- W -> Wtp packed B-fragment order.
// Wtp 16B-chunk index: (((proj*4+nt)*16 + kb)*2 + k2)*64 + quad*16 + l15
// holding W[k = kb*64+k2*32+quad*8 .. +8][n = proj*64+nt*16+l15].
__global__ void wt_transpose(const void* __restrict__ Wk, const void* __restrict__ Wq,
                             const void* __restrict__ Wv, u16* __restrict__ Wtp,
                             const int* __restrict__ flag) {
    const int isbf = *flag;
    int r = blockIdx.x;          // global output col 0..191
    int p = r >> 6;              // 0=q 1=k 2=v
    int n = r & 63;
    int nt = n >> 4, nl = n & 15;
    const void* W = (p == 0) ? Wq : (p == 1) ? Wk : Wv;
    int k0 = threadIdx.x * 4;    // 4 consecutive k per thread
    int kb = k0 >> 6, k2 = (k0 >> 5) & 1, quad = (k0 >> 3) & 3, half = (k0 >> 2) & 1;
    ushort4 v;
    if (isbf) {
        const u16* Wb = (const u16*)W;
        v.x = Wb[(k0 + 0) * HH + n]; v.y = Wb[(k0 + 1) * HH + n];
        v.z = Wb[(k0 + 2) * HH + n]; v.w = Wb[(k0 + 3) * HH + n];
    } else {
        const float* Wf = (const float*)W;
        v.x = f2bf(Wf[(k0 + 0) * HH + n]); v.y = f2bf(Wf[(k0 + 1) * HH + n]);
        v.z = f2bf(Wf[(k0 + 2) * HH + n]); v.w = f2bf(Wf[(k0 + 3) * HH + n]);
    }
    size_t off16 = ((size_t)((p * 4 + nt) * 16 + kb) * 2 + k2) * 64 + quad * 16 + nl;
    *reinterpret_cast<ushort4*>(Wtp + off16 * 8 + half * 4) = v;
}

// ---------------- QKV projection v4: fused LDS transpose, one barrier.
// 1024 blocks x 256 thr (4 waves). Block = 16 rows of x; the FULL K=1024 is staged
// into 32KB LDS with contiguous global reads, then the k-loop runs barrier-free:
// A-frags from LDS (swizzled), B-frags from L2-resident Wtp (contiguous 1KB/instr).
// Wave w computes col-tile w of each of q,k,v.
__global__ __launch_bounds__(256) void qkv_proj(const void* __restrict__ x,
                                                const u16* __restrict__ Wtp,
                                                u16* __restrict__ qo, u16* __restrict__ ko,
                                                u16* __restrict__ vo, const int* __restrict__ flag) {
    __shared__ __align__(16) u16 xs[16 * 1024];   // [row][k], 16B chunks swizzled by row&7
    __shared__ __align__(16) u16 tls[4][3][256];  // per-wave, per-proj 16x16 transpose tile
    const int isbf = *flag;
    const int tid = threadIdx.x;
    const int lane = tid & 63;
    const int w = tid >> 6;
    const int l15 = lane & 15;
    const int quad = lane >> 4;
    int phys = blockIdx.x;
    int rb = (phys & 7) * 128 + (phys >> 3);      // XCD-affine 16-row group, 0..1023
    const int g0r = rb * 16;

    // ---- stage 16 rows of x (contiguous reads; swizzled 16B-chunk writes)
    #pragma unroll
    for (int j = 0; j < 8; j++) {
        int c = tid + j * 256;                    // 2048 chunks: row = c>>7, ck = c&127
        int row = c >> 7, ck = c & 127;
        int dst = row * 1024 + ((ck ^ (row & 7)) << 3);
        if (isbf) {
            uint4 d = *reinterpret_cast<const uint4*>((const u16*)x + (size_t)(g0r + row) * CC + ck * 8);
            *reinterpret_cast<uint4*>(xs + dst) = d;
        } else {
            const float4* pf = reinterpret_cast<const float4*>((const float*)x + (size_t)(g0r + row) * CC + ck * 8);
            float4 a0 = pf[0], a1 = pf[1];
            ushort4 lo; lo.x = f2bf(a0.x); lo.y = f2bf(a0.y); lo.z = f2bf(a0.z); lo.w = f2bf(a0.w);
            ushort4 hi; hi.x = f2bf(a1.x); hi.y = f2bf(a1.y); hi.z = f2bf(a1.z); hi.w = f2bf(a1.w);
            *reinterpret_cast<ushort4*>(xs + dst) = lo;
            *reinterpret_cast<ushort4*>(xs + dst + 4) = hi;
        }
    }
    __syncthreads();                              // the ONLY block-wide barrier

    f32x4 zero = {0.f, 0.f, 0.f, 0.f};
    f32x4 acc[3];                                 // proj 0=q 1=k 2=v, col-tile w each
    #pragma unroll
    for (int i = 0; i < 3; i++) acc[i] = zero;

    for (int kb = 0; kb < 16; kb++) {
        #pragma unroll
        for (int k2 = 0; k2 < 2; k2++) {
            int ck = kb * 8 + k2 * 4 + quad;
            short8 af = *reinterpret_cast<const short8*>(xs + l15 * 1024 + ((ck ^ (l15 & 7)) << 3));
            #pragma unroll
            for (int p = 0; p < 3; p++) {
                short8 bf = *reinterpret_cast<const short8*>(
                    Wtp + ((((size_t)(p * 4 + w) * 16 + kb) * 2 + k2) * 64 + lane) * 8);
                acc[p] = __builtin_amdgcn_mfma_f32_16x16x32_bf16(af, bf, acc[p], 0, 0, 0);
            }
        }
    }

    // ---- epilogue: per-wave 16x16 LDS transpose, 8B coalesced stores
    const float qscale = 0.18033688011112042f;    // log2(e)/8
    #pragma unroll
    for (int p = 0; p < 3; p++) {
        if (p < 2) {
            float sc = (p == 0) ? qscale : 1.f;
            #pragma unroll
            for (int r = 0; r < 4; r++)           // [t(16)][c(16)]
                tls[w][p][(quad * 4 + r) * 16 + l15] = f2bf(acc[p][r] * sc);
        } else {
            #pragma unroll
            for (int r = 0; r < 4; r++)           // [c(16)][t(16)]
                tls[w][p][l15 * 16 + quad * 4 + r] = f2bf(acc[p][r]);
        }
    }
    // same-wave LDS RAW: compiler inserts lgkmcnt wait; no barrier needed
    #pragma unroll
    for (int p = 0; p < 2; p++) {                 // q, k: row-major (g0r+t)*64 + w*16+c
        int t = lane >> 2, seg = lane & 3;
        ushort4 d = *reinterpret_cast<const ushort4*>(&tls[w][p][t * 16 + seg * 4]);
        u16* dst = (p == 0) ? qo : ko;
        *reinterpret_cast<ushort4*>(dst + (size_t)(g0r + t) * HH + w * 16 + seg * 4) = d;
    }
    {                                             // v: vo[b][kt][h][64keys]
        int c = lane >> 2, seg = lane & 3;
        ushort4 d = *reinterpret_cast<const ushort4*>(&tls[w][2][c * 16 + seg * 4]);
        int b = rb >> 8;
        int kt = (g0r & 4095) >> 6;
        int toff = g0r & 63;
        *reinterpret_cast<ushort4*>(vo + ((size_t)((b * 64 + kt) * 64 + w * 16 + c)) * 64 + toff + seg * 4) = d;
    }
}

// ---------------- causal flash attention, 64 q-rows/block, split-K over 64-key tiles.
// vo is ktile-packed -> both K and V staging are contiguous 8KB reads.
// Pipeline: K/V for tile kt+nsplit are prefetched into REGISTERS while tile kt
// computes (T14 async-STAGE split); ds_write happens after the next barrier.
// Split-K combine is SLOT-BASED (no atomics); splits dispatched high-qt first.
__global__ __launch_bounds__(256) void attn(const u16* __restrict__ qp, const u16* __restrict__ kp,
                                            const u16* __restrict__ vp, float* __restrict__ acco,
                                            float* __restrict__ accl, void* __restrict__ outv,
                                            const int* __restrict__ flag, int nsplit) {
    __shared__ __align__(16) u16 kst[64 * 64];   // (key, h), swizzled
    __shared__ __align__(16) u16 vts[64 * 64];   // (h, key), swizzled
    __shared__ __align__(16) u16 pb[4][16 * 64]; // per-wave P
    const int isbf = *flag;
    const int tid = threadIdx.x;
    const int lane = tid & 63;
    const int w = tid >> 6;           // 0..3
    const int l15 = lane & 15;
    const int quad = lane >> 4;

    int u = blockIdx.x;
    int b, qt, ks;
    if (nsplit == 1) {
        b = u >> 6;
        int raw = u & 63;
        qt = (raw & 1) ? (63 - (raw >> 1)) : (raw >> 1);
        ks = 0;
    } else {
        int per = 64 * nsplit;
        b = u / per;
        int rem = u - b * per;
        int i = rem / nsplit;
        qt = 63 - i;                  // descending qt: long blocks launch first
        ks = rem - i * nsplit;
    }
    int qbase = qt * 64;
    int diag = qt;
    int nkt = diag + 1;
    if (ks >= nkt) return;

    short8 aq[2];
    {
        const u16* qrow = qp + (size_t)(b * TT + qbase + w * 16 + l15) * HH;
        aq[0] = *reinterpret_cast<const short8*>(qrow + quad * 8);
        aq[1] = *reinterpret_cast<const short8*>(qrow + 32 + quad * 8);
    }

    // staging addresses (kt-invariant)
    const int cc0 = tid, cc1 = tid + 256;
    const int dst0 = swz(cc0 >> 3, cc0 & 7);
    const int dst1 = swz(cc1 >> 3, cc1 & 7);
    const u16* kbase = kp + (size_t)b * TT * HH;        // + kt*4096 + cc*8
    const u16* vbase = vp + (size_t)b * 64 * 64 * 64;   // + kt*4096 + cc*8

    f32x4 zero = {0.f, 0.f, 0.f, 0.f};
    f32x4 o[4];
    #pragma unroll
    for (int i = 0; i < 4; i++) o[i] = zero;
    f32x4 lsum = zero;

    // prologue prefetch: tile ks into registers
    uint4 rk0 = *reinterpret_cast<const uint4*>(kbase + (size_t)ks * 4096 + cc0 * 8);
    uint4 rk1 = *reinterpret_cast<const uint4*>(kbase + (size_t)ks * 4096 + cc1 * 8);
    uint4 rv0 = *reinterpret_cast<const uint4*>(vbase + (size_t)ks * 4096 + cc0 * 8);
    uint4 rv1 = *reinterpret_cast<const uint4*>(vbase + (size_t)ks * 4096 + cc1 * 8);

    for (int kt = ks; kt < nkt; kt += nsplit) {
        __syncthreads();              // previous iter's LDS reads done
        *reinterpret_cast<uint4*>(&kst[dst0]) = rk0;
        *reinterpret_cast<uint4*>(&kst[dst1]) = rk1;
        *reinterpret_cast<uint4*>(&vts[dst0]) = rv0;
        *reinterpret_cast<uint4*>(&vts[dst1]) = rv1;
        __syncthreads();              // staging visible
        // issue next tile's loads NOW; they fly under this tile's compute
        int ktn = kt + nsplit;
        if (ktn < nkt) {
            rk0 = *reinterpret_cast<const uint4*>(kbase + (size_t)ktn * 4096 + cc0 * 8);
            rk1 = *reinterpret_cast<const uint4*>(kbase + (size_t)ktn * 4096 + cc1 * 8);
            rv0 = *reinterpret_cast<const uint4*>(vbase + (size_t)ktn * 4096 + cc0 * 8);
            rv1 = *reinterpret_cast<const uint4*>(vbase + (size_t)ktn * 4096 + cc1 * 8);
        }
        // S = Q K^T (log2 domain via q pre-scale)
        f32x4 s[4];
        #pragma unroll
        for (int i = 0; i < 4; i++) s[i] = zero;
        __builtin_amdgcn_s_setprio(1);
        #pragma unroll
        for (int k2 = 0; k2 < 2; k2++) {
            #pragma unroll
            for (int nt = 0; nt < 4; nt++) {
                short8 bf = *reinterpret_cast<const short8*>(&kst[swz(nt * 16 + l15, k2 * 4 + quad)]);
                s[nt] = __builtin_amdgcn_mfma_f32_16x16x32_bf16(aq[k2], bf, s[nt], 0, 0, 0);
            }
        }
        __builtin_amdgcn_s_setprio(0);
        // p = exp2(s), causal mask on diagonal tile
        const int rg = qbase + w * 16 + quad * 4;
        const bool dm = (kt == diag);
        #pragma unroll
        for (int nt = 0; nt < 4; nt++) {
            int key = kt * 64 + nt * 16 + l15;
            #pragma unroll
            for (int r = 0; r < 4; r++) {
                float p = __builtin_amdgcn_exp2f(s[nt][r]);
                if (dm && key > rg + r) p = 0.f;
                s[nt][r] = p;
            }
        }
        #pragma unroll
        for (int nt = 0; nt < 4; nt++) lsum = lsum + s[nt];
        // P (C/D layout) -> per-wave LDS A-layout (same-wave RAW)
        #pragma unroll
        for (int nt = 0; nt < 4; nt++) {
            int chunk = nt * 2 + (l15 >> 3);
            int off = l15 & 7;
            #pragma unroll
            for (int r = 0; r < 4; r++) {
                int row = quad * 4 + r;
                pb[w][row * 64 + ((chunk ^ (row & 7)) << 3) + off] = f2bf(s[nt][r]);
            }
        }
        // O += P V
        __builtin_amdgcn_s_setprio(1);
        #pragma unroll
        for (int k2 = 0; k2 < 2; k2++) {
            short8 ap = *reinterpret_cast<const short8*>(&pb[w][swz(l15, k2 * 4 + quad)]);
            #pragma unroll
            for (int nt = 0; nt < 4; nt++) {
                short8 bv = *reinterpret_cast<const short8*>(&vts[swz(nt * 16 + l15, k2 * 4 + quad)]);
                o[nt] = __builtin_amdgcn_mfma_f32_16x16x32_bf16(ap, bv, o[nt], 0, 0, 0);
            }
        }
        __builtin_amdgcn_s_setprio(0);
    }

    #pragma unroll
    for (int d = 1; d < 16; d <<= 1) {
        f32x4 t;
        #pragma unroll
        for (int r = 0; r < 4; r++) t[r] = __shfl_xor(lsum[r], d);
        lsum = lsum + t;
    }
    const int g0 = b * TT + qbase + w * 16 + quad * 4;

    if (nsplit == 1) {
        f32x4 inv;
        #pragma unroll
        for (int r = 0; r < 4; r++) inv[r] = 1.0f / lsum[r];
        if (isbf) {
            u16* outp = (u16*)outv;
            #pragma unroll
            for (int nt = 0; nt < 4; nt++)
                #pragma unroll
                for (int r = 0; r < 4; r++)
                    outp[(size_t)(g0 + r) * HH + nt * 16 + l15] = f2bf(o[nt][r] * inv[r]);
        } else {
            float* outp = (float*)outv;
            #pragma unroll
            for (int nt = 0; nt < 4; nt++)
                #pragma unroll
                for (int r = 0; r < 4; r++)
                    outp[(size_t)(g0 + r) * HH + nt * 16 + l15] = o[nt][r] * inv[r];
        }
    } else {
        // slot-based partial writes: each (b,qt,ks) owns distinct rows of its slot
        float* accos = acco + (size_t)ks * (BB * TT * HH);
        float* accls = accl + (size_t)ks * (BB * TT);
        #pragma unroll
        for (int nt = 0; nt < 4; nt++)
            #pragma unroll
            for (int r = 0; r < 4; r++)
                accos[(size_t)(g0 + r) * HH + nt * 16 + l15] = o[nt][r];
        if (l15 == 0) {
            #pragma unroll
            for (int r = 0; r < 4; r++) accls[g0 + r] = lsum[r];
        }
    }
}

// ---------------- finalize: out = (sum over active slots of acco) / (sum accl)
__global__ __launch_bounds__(256) void attn_finalize(const float* __restrict__ acco,
                                                     const float* __restrict__ accl,
                                                     void* __restrict__ outv,
                                                     const int* __restrict__ flag, int nsplit) {
    const int isbf = *flag;
    int i = blockIdx.x * blockDim.x + threadIdx.x;   // float4 index over B*T*H
    int row = i >> 4;
    int qt = (row & (TT - 1)) >> 6;
    int nact = min(nsplit, qt + 1);
    float4 ov = reinterpret_cast<const float4*>(acco)[i];
    float l = accl[row];
    for (int s = 1; s < nact; s++) {
        float4 t = reinterpret_cast<const float4*>(acco + (size_t)s * (BB * TT * HH))[i];
        ov.x += t.x; ov.y += t.y; ov.z += t.z; ov.w += t.w;
        l += accl[(size_t)s * (BB * TT) + row];
    }
    float inv = 1.0f / l;
    if (isbf) {
        ushort4 s;
        s.x = f2bf(ov.x * inv); s.y = f2bf(ov.y * inv);
        s.z = f2bf(ov.z * inv); s.w = f2bf(ov.w * inv);
        reinterpret_cast<ushort4*>(outv)[i] = s;
    } else {
        float4 s = {ov.x * inv, ov.y * inv, ov.z * inv, ov.w * inv};
        reinterpret_cast<float4*>(outv)[i] = s;
    }
}

extern "C" void kernel_launch(void* const* d_in, const int* in_sizes, int n_in,
                              void* d_out, int out_size, void* d_ws, size_t ws_size,
                              hipStream_t stream) {
    const void* x  = d_in[0];
    const void* Wk = d_in[1];
    const void* Wq = d_in[2];
    const void* Wv = d_in[3];
    char* ws = (char*)d_ws;
    // ws: qo 0-2M | ko 2-4M | vo 4-6M | Wtp @6M(384K) | flag @6.75M
    //     acco @7M (nsplit slots x 4M) | accl @39M (nsplit slots x 64K)
    u16* qo = (u16*)(ws);
    u16* ko = (u16*)(ws + (size_t)2 * 1024 * 1024);
    u16* vo = (u16*)(ws + (size_t)4 * 1024 * 1024);
    u16* Wtp = (u16*)(ws + (size_t)6 * 1024 * 1024);
    int* flag = (int*)(ws + (size_t)6 * 1024 * 1024 + 768 * 1024);
    float* acco = (float*)(ws + (size_t)7 * 1024 * 1024);
    float* accl = (float*)(ws + (size_t)39 * 1024 * 1024);

    const size_t need_split = (size_t)40 * 1024 * 1024;
    const int nsplit = (ws_size >= need_split) ? 8 : 1;

    detect_dtype<<<1, 64, 0, stream>>>((const u16*)x, flag);
    wt_transpose<<<192, 256, 0, stream>>>(Wk, Wq, Wv, Wtp, flag);
    qkv_proj<<<1024, 256, 0, stream>>>(x, Wtp, qo, ko, vo, flag);
    if (nsplit > 1) {
        attn<<<BB * 64 * nsplit, 256, 0, stream>>>(qo, ko, vo, acco, accl, d_out, flag, nsplit);
        attn_finalize<<<(BB * TT * HH / 4) / 256, 256, 0, stream>>>(acco, accl, d_out, flag, nsplit);
    } else {
        attn<<<BB * 64, 256, 0, stream>>>(qo, ko, vo, acco, accl, d_out, flag, 1);
    }
}